// Round 3
// baseline (502.177 us; speedup 1.0000x reference)
//
#include <hip/hip_runtime.h>
#include <hip/hip_bf16.h>

// KronLinear: out = x @ (sum_r kron(a_r, b_r)) + bias
// M=8192 tokens, K=4096=(i,k_b), N=4096=(j,l), RANK=64.
// R5: pack-x = LDS tile transpose (128 rows x 256 k per block): contiguous
//     1KB/wave reads AND contiguous 8KB blob writes; XOR-swizzled LDS
//     (col ^ (row&31)) conflict-free both sides. Xp blob layout reverted to
//     (c*128+mm) so gemm's global_load_lds source is linear again (R2's
//     per-lane permutation quadrupled A-staging requests -> 242->250 regress).
//     Gemm keeps depth-3 ring + counted vmcnt(8).

#define M_DIM 8192
#define N_DIM 4096
#define K_DIM 4096
#define KT_COUNT 128   // K_DIM / 32
#define NBUILD 2048    // build_w blocks
#define NPACK 1024     // pack blocks: 64 M-panels x 16 k-groups

typedef __attribute__((ext_vector_type(8))) short short8;
typedef __attribute__((ext_vector_type(4))) float floatx4;

typedef __attribute__((address_space(1))) void gvoid_t;
typedef __attribute__((address_space(3))) void lvoid_t;

static __device__ __forceinline__ void gl_lds16(const void* g, const void* l) {
  __builtin_amdgcn_global_load_lds((gvoid_t*)(unsigned long long)g,
                                   (lvoid_t*)(unsigned int)(unsigned long long)l,
                                   16, 0, 0);
}

static __device__ __forceinline__ unsigned short f2bf(float f) {
  unsigned int u = __builtin_bit_cast(unsigned int, f);
  u = (u + 0x7fffu + ((u >> 16) & 1u)) >> 16;  // RNE
  return (unsigned short)u;
}

// ---------------------------------------------------------------------------
// Fused prep, 512-thread blocks.
// blocks [0, NBUILD): build W^T (256 active threads; latency/VALU-bound,
//   dispatched first to overlap pack's BW streaming).
// blocks [NBUILD, NBUILD+NPACK): pack x via LDS tile transpose.
//   Block = (M0, kg): rows M0*128..+127, k = kg*256..+255.
//   Read: 8 passes, wave = 2 rows x 1KB contiguous.
//   LDS: chunk (row, col8) stored at [row*32 + (col8 ^ (row&31))] (16B units).
//   Write: 8 passes; pass q writes complete blob kt=kg*8+q, thread t -> chunk
//   t (c=t>>7, mm=t&127), 8KB contiguous; source lds[mm*32+((q*4+c)^(mm&31))].
//
// Xp/Wp blob (T0, kt) = 8KB: chunk (c*128 + row) holds row/col, k = kt*32 +
// c*8..+7 as 8 bf16.
// ---------------------------------------------------------------------------
__global__ __launch_bounds__(512) void prep_kernel(
    const float* __restrict__ x, const float* __restrict__ a,
    const float* __restrict__ b, unsigned short* __restrict__ Xp,
    unsigned short* __restrict__ Wp) {
  __shared__ short8 smem[4096];  // 64 KB (build_w aliases first 4 KB as float)
  const int bid = blockIdx.x;
  const int t = threadIdx.x;

  if (bid < NBUILD) {
    // ---- build W^T: wT[n=(j*64+l)][i*64+k_b] = sum_r a[r,i,j]*b[r,k_b,l]
    float* lds_a = (float*)smem;
    const int rg = bid & 255;
    const int i = rg >> 2;
    const int j0 = (rg & 3) * 16;
    const int k0 = (bid >> 8) * 8;  // 0..56

    if (t < 256) {  // stage a[r, i, j0..j0+15] for all r: 1024 floats
      const int r = t >> 2, jq = t & 3;
      float4 v = ((const float4*)(a + (size_t)r * 4096 + i * 64 + j0))[jq];
      ((float4*)lds_a)[r * 4 + jq] = v;
    }
    __syncthreads();

    if (t < 256) {
      const int l = t & 63;
      const int jj = t >> 6;  // 0..3
      float acc[4][8];
#pragma unroll
      for (int jp = 0; jp < 4; ++jp)
#pragma unroll
        for (int kb = 0; kb < 8; ++kb) acc[jp][kb] = 0.f;

      const float* bb = b + k0 * 64 + l;
#pragma unroll 4
      for (int r = 0; r < 64; ++r) {
        float4 aj = ((const float4*)lds_a)[r * 4 + jj];
        float bv[8];
#pragma unroll
        for (int kb = 0; kb < 8; ++kb) bv[kb] = bb[(size_t)r * 4096 + kb * 64];
        const float av[4] = {aj.x, aj.y, aj.z, aj.w};
#pragma unroll
        for (int jp = 0; jp < 4; ++jp)
#pragma unroll
          for (int kb = 0; kb < 8; ++kb)
            acc[jp][kb] = fmaf(av[jp], bv[kb], acc[jp][kb]);
      }

      const int kt = (i * 64 + k0) >> 5;
      const int c = (k0 & 31) >> 3;
#pragma unroll
      for (int jp = 0; jp < 4; ++jp) {
        const int j = j0 + jj * 4 + jp;
        const int n = j * 64 + l;
        const int blob = (n >> 7) * KT_COUNT + kt;
        const int pos = c * 128 + (n & 127);
        short8 o;
#pragma unroll
        for (int kb = 0; kb < 8; ++kb) o[kb] = (short)f2bf(acc[jp][kb]);
        *(short8*)(Wp + (size_t)blob * 4096 + pos * 8) = o;
      }
    }
  } else {
    // ---- pack x: LDS tile transpose, contiguous reads AND writes
    const int pid = bid - NBUILD;
    const int M0 = pid >> 4;   // 0..63
    const int kg = pid & 15;   // 0..15
    const int rsub = t >> 5;   // 0..15
    const int col8 = t & 31;   // 16B chunk within the 256-k slice

#pragma unroll
    for (int p = 0; p < 8; ++p) {
      const int row = p * 16 + rsub;
      const float* src =
          x + (size_t)(M0 * 128 + row) * K_DIM + kg * 256 + col8 * 8;
      float4 v0 = ((const float4*)src)[0];
      float4 v1 = ((const float4*)src)[1];
      short8 o;
      o[0] = (short)f2bf(v0.x); o[1] = (short)f2bf(v0.y);
      o[2] = (short)f2bf(v0.z); o[3] = (short)f2bf(v0.w);
      o[4] = (short)f2bf(v1.x); o[5] = (short)f2bf(v1.y);
      o[6] = (short)f2bf(v1.z); o[7] = (short)f2bf(v1.w);
      smem[row * 32 + (col8 ^ (row & 31))] = o;
    }
    __syncthreads();

    const int c = t >> 7, mm = t & 127;
    unsigned short* dst =
        Xp + (size_t)(M0 * KT_COUNT + kg * 8) * 4096 + t * 8;
#pragma unroll
    for (int q = 0; q < 8; ++q) {
      short8 v = smem[mm * 32 + ((q * 4 + c) ^ (mm & 31))];
      *(short8*)(dst + (size_t)q * 4096) = v;
    }
  }
}

// ---------------------------------------------------------------------------
// GEMM: C = Xp @ Wp^T + bias.  256x256 tile, BK=32, 512 threads (8 waves,
// 2M x 4N), per-wave 128x64 output = acc[8][4] of 16x16 frags.
// LDS: 4-deep ring of K-steps (A 16KB + B 16KB each) = 128 KiB.
// Prefetch distance 3: issue step t+3, single counted vmcnt(8)/K-step
// (8 loads in flight = steps t+2,t+3; forces t+1 landed, ~2 iters of slack).
// Ring-overlap safe: write target (kt+3)&3 = buffer last read at kt-1,
// drained by that iteration's lgkmcnt(0) + trailing barrier.
// Staging sources linear (t*8): each wave reads 1KB contiguous per gl_lds.
// XCD swizzle: bid&7 -> XCD owns 2 N-panels (4MB Wp slice pinned in its L2).
// ---------------------------------------------------------------------------
#define BAR() asm volatile("s_barrier" ::: "memory")
#define WAIT_VM(N) asm volatile("s_waitcnt vmcnt(" #N ")" ::: "memory")
#define WAIT_LGKM0() asm volatile("s_waitcnt lgkmcnt(0)" ::: "memory")

__global__ __launch_bounds__(512, 2) void gemm_kernel(
    const unsigned short* __restrict__ Xp, const unsigned short* __restrict__ Wp,
    const float* __restrict__ bias, float* __restrict__ out) {
  __shared__ short8 As[4][2][512];  // [ring buf][row half][chunk]  64 KiB
  __shared__ short8 Bs[4][2][512];  // [ring buf][col half][chunk]  64 KiB

  const int bid = blockIdx.x;
  const int xcd = bid & 7;
  const int pos = bid >> 3;            // 0..63
  const int N0 = xcd * 2 + (pos & 1);  // 0..15 (256-col panels)
  const int M0 = pos >> 1;             // 0..31 (256-row panels)

  const int t = threadIdx.x;
  const int wave = t >> 6, lane = t & 63;
  const int l16 = lane & 15, quad = lane >> 4;
  const int wm = wave & 1;   // A half (128 rows)
  const int wn = wave >> 1;  // 0..3 (64-col quarter)

  floatx4 acc[8][4];
#pragma unroll
  for (int mt = 0; mt < 8; ++mt)
#pragma unroll
    for (int nt = 0; nt < 4; ++nt) acc[mt][nt] = (floatx4){0.f, 0.f, 0.f, 0.f};

  const unsigned short* gA0 = Xp + (size_t)(M0 * 2 + 0) * KT_COUNT * 4096 + (size_t)t * 8;
  const unsigned short* gA1 = Xp + (size_t)(M0 * 2 + 1) * KT_COUNT * 4096 + (size_t)t * 8;
  const unsigned short* gB0 = Wp + (size_t)(N0 * 2 + 0) * KT_COUNT * 4096 + (size_t)t * 8;
  const unsigned short* gB1 = Wp + (size_t)(N0 * 2 + 1) * KT_COUNT * 4096 + (size_t)t * 8;

  // ---- prologue: stage K-steps 0,1,2 (12 loads); require step 0 landed.
#pragma unroll
  for (int s = 0; s < 3; ++s) {
    gl_lds16(gA0 + (size_t)s * 4096, &As[s][0][t]);
    gl_lds16(gA1 + (size_t)s * 4096, &As[s][1][t]);
    gl_lds16(gB0 + (size_t)s * 4096, &Bs[s][0][t]);
    gl_lds16(gB1 + (size_t)s * 4096, &Bs[s][1][t]);
  }
  WAIT_VM(8);  // step 0 complete; steps 1,2 (8 loads) may stay in flight
  BAR();

  const int ra = quad * 128 + l16;                  // A chunk base
  const int rb = quad * 128 + (wn & 1) * 64 + l16;  // B chunk base
  const int bh = wn >> 1;                           // B half

#pragma unroll 2
  for (int kt = 0; kt < KT_COUNT; ++kt) {
    const int tb = kt & 3;
    const int db = (kt + 3) & 3;
    const size_t soff =
        (size_t)((kt + 3 < KT_COUNT) ? kt + 3 : KT_COUNT - 1) * 4096;

    short8 bf[4], af[4];

    // ---------------- phase 0: B frags + A rows 0..63, stage A(t+3)
#pragma unroll
    for (int nt = 0; nt < 4; ++nt) bf[nt] = Bs[tb][bh][rb + nt * 16];
#pragma unroll
    for (int m = 0; m < 4; ++m) af[m] = As[tb][wm][ra + m * 16];
    gl_lds16(gA0 + soff, &As[db][0][t]);
    gl_lds16(gA1 + soff, &As[db][1][t]);
    BAR();
    WAIT_LGKM0();
    __builtin_amdgcn_sched_barrier(0);
    __builtin_amdgcn_s_setprio(1);
#pragma unroll
    for (int m = 0; m < 4; ++m)
#pragma unroll
      for (int nt = 0; nt < 4; ++nt)
        acc[m][nt] = __builtin_amdgcn_mfma_f32_16x16x32_bf16(
            af[m], bf[nt], acc[m][nt], 0, 0, 0);
    __builtin_amdgcn_s_setprio(0);
    __builtin_amdgcn_sched_barrier(0);
    BAR();

    // ---------------- phase 1: A rows 64..127, stage B(t+3), counted vmcnt
#pragma unroll
    for (int m = 0; m < 4; ++m) af[m] = As[tb][wm][ra + (4 + m) * 16];
    gl_lds16(gB0 + soff, &Bs[db][0][t]);
    gl_lds16(gB1 + soff, &Bs[db][1][t]);
    WAIT_VM(8);  // steps t+2,t+3 in flight; forces step t+1 landed
    BAR();
    WAIT_LGKM0();
    __builtin_amdgcn_sched_barrier(0);
    __builtin_amdgcn_s_setprio(1);
#pragma unroll
    for (int m = 0; m < 4; ++m)
#pragma unroll
      for (int nt = 0; nt < 4; ++nt)
        acc[4 + m][nt] = __builtin_amdgcn_mfma_f32_16x16x32_bf16(
            af[m], bf[nt], acc[4 + m][nt], 0, 0, 0);
    __builtin_amdgcn_s_setprio(0);
    __builtin_amdgcn_sched_barrier(0);
    BAR();
  }

  // ---- epilogue
  const int col_base = N0 * 256 + wn * 64;
  const int row_base = M0 * 256 + wm * 128;
#pragma unroll
  for (int nt = 0; nt < 4; ++nt) {
    const int col = col_base + nt * 16 + l16;
    const float bv = bias[col];
#pragma unroll
    for (int mt = 0; mt < 8; ++mt) {
      floatx4 v = acc[mt][nt];
#pragma unroll
      for (int r4 = 0; r4 < 4; ++r4) {
        const int row = row_base + mt * 16 + quad * 4 + r4;
        out[(size_t)row * N_DIM + col] = v[r4] + bv;
      }
    }
  }
}

extern "C" void kernel_launch(void* const* d_in, const int* in_sizes, int n_in,
                              void* d_out, int out_size, void* d_ws, size_t ws_size,
                              hipStream_t stream) {
  const float* x = (const float*)d_in[0];     // 8192*4096
  const float* a = (const float*)d_in[1];     // 64*64*64 (r,i,j)
  const float* b = (const float*)d_in[2];     // 64*64*64 (r,k,l)
  const float* bias = (const float*)d_in[3];  // 4096
  float* out = (float*)d_out;

  unsigned short* Xp = (unsigned short*)d_ws;        // 67MB
  unsigned short* Wp = Xp + (size_t)M_DIM * K_DIM;   // 33.5MB

  prep_kernel<<<NBUILD + NPACK, 512, 0, stream>>>(x, a, b, Xp, Wp);
  gemm_kernel<<<512, 512, 0, stream>>>(Xp, Wp, bias, out);
}

// Round 5
// 474.248 us; speedup vs baseline: 1.0589x; 1.0589x over previous
//
#include <hip/hip_runtime.h>
#include <hip/hip_bf16.h>

// KronLinear: out = x @ (sum_r kron(a_r, b_r)) + bias
// M=8192 tokens, K=4096=(i,k_b), N=4096=(j,l), RANK=64.
// R7 = R6 resubmitted verbatim (R6 bench died to an infra flake: "container
// failed twice", no profile). Source audited for container-killers: no OOB,
// gl_lds dest is wave-uniform+lane*16, uniform barriers. Experiment intent:
// prep split into TWO kernels (build_w / pack_x) so rocprof reports each
// dispatch separately -- 4 rounds of pack rewrites never moved prep (~240us,
// 6x streaming floor) and the fused kernel's counters were invisible.
// build_w stages its b-slice through LDS double-buffer via global_load_lds
// (was: 512 scalar global loads/thread, latency suspect). pack_x keeps the
// R5 LDS-transpose at 32KB/block. gemm is R1's exact depth-2/vmcnt(4) code
// (242-244us measured; depth-3 cost ~7us).

#define M_DIM 8192
#define N_DIM 4096
#define K_DIM 4096
#define KT_COUNT 128   // K_DIM / 32

typedef __attribute__((ext_vector_type(8))) short short8;
typedef __attribute__((ext_vector_type(4))) float floatx4;

typedef __attribute__((address_space(1))) void gvoid_t;
typedef __attribute__((address_space(3))) void lvoid_t;

static __device__ __forceinline__ void gl_lds16(const void* g, const void* l) {
  __builtin_amdgcn_global_load_lds((gvoid_t*)(unsigned long long)g,
                                   (lvoid_t*)(unsigned int)(unsigned long long)l,
                                   16, 0, 0);
}

static __device__ __forceinline__ unsigned short f2bf(float f) {
  unsigned int u = __builtin_bit_cast(unsigned int, f);
  u = (u + 0x7fffu + ((u >> 16) & 1u)) >> 16;  // RNE
  return (unsigned short)u;
}

#define BAR() asm volatile("s_barrier" ::: "memory")
#define WAIT_VM(N) asm volatile("s_waitcnt vmcnt(" #N ")" ::: "memory")
#define WAIT_LGKM0() asm volatile("s_waitcnt lgkmcnt(0)" ::: "memory")

// ---------------------------------------------------------------------------
// build_w: wT[n=(j*64+l)][i*64+k_b] = sum_r a[r,i,j]*b[r,k_b,l]
// 2048 blocks x 256 threads. Block = (i, j0-group of 16, k0-group of 8).
// b-slice (64 r x 8 kb x 64 l = 128KB) staged through LDS in 8 groups of
// 8 r (16KB each), double-buffered, via global_load_lds (coalesced 16B/lane,
// one group's stage hides under the previous group's 512 FMA + LDS reads).
// Replaces 512 scalar global b-loads per thread (the latency suspect).
// Wp blob (T0, kt) = 8KB: chunk (c*128 + n) holds col n, k = kt*32+c*8..+7.
// ---------------------------------------------------------------------------
__global__ __launch_bounds__(256) void build_w_kernel(
    const float* __restrict__ a, const float* __restrict__ b,
    unsigned short* __restrict__ Wp) {
  __shared__ float lds_a[1024];     // 4 KB: a[r][16 j]
  __shared__ float lds_b[2][4096];  // 2 x 16 KB: [8 r][512 (kb,l)]
  const int bid = blockIdx.x;
  const int t = threadIdx.x;
  const int rg = bid & 255;
  const int i = rg >> 2;
  const int j0 = (rg & 3) * 16;
  const int k0 = (bid >> 8) * 8;  // 0..56

  {  // stage a[r, i, j0..j0+15] for all r: 1024 floats
    const int r = t >> 2, jq = t & 3;
    float4 v = ((const float4*)(a + (size_t)r * 4096 + i * 64 + j0))[jq];
    ((float4*)lds_a)[r * 4 + jq] = v;
  }

  const float* bsrc = b + k0 * 64;  // row r at bsrc + r*4096 (512 floats used)

  // prologue: stage r-group 0 (16 KB, 4 x gl_lds per thread)
#pragma unroll
  for (int p = 0; p < 4; ++p) {
    const int idx = p * 256 + t;  // float4 index into the 16KB slab
    gl_lds16(bsrc + (size_t)(idx >> 7) * 4096 + (idx & 127) * 4,
             &((float4*)lds_b[0])[idx]);
  }
  WAIT_VM(0);
  __syncthreads();

  const int l = t & 63;
  const int jj = t >> 6;  // 0..3
  float acc[4][8];
#pragma unroll
  for (int jp = 0; jp < 4; ++jp)
#pragma unroll
    for (int kb = 0; kb < 8; ++kb) acc[jp][kb] = 0.f;

  for (int g = 0; g < 8; ++g) {
    const int cur = g & 1;
    if (g < 7) {  // prefetch next r-group into the other buffer
      const float* nb = bsrc + (size_t)(g + 1) * 8 * 4096;
#pragma unroll
      for (int p = 0; p < 4; ++p) {
        const int idx = p * 256 + t;
        gl_lds16(nb + (size_t)(idx >> 7) * 4096 + (idx & 127) * 4,
                 &((float4*)lds_b[cur ^ 1])[idx]);
      }
    }
#pragma unroll
    for (int rr = 0; rr < 8; ++rr) {
      float4 aj = ((const float4*)lds_a)[(g * 8 + rr) * 4 + jj];
      float bv[8];
#pragma unroll
      for (int kb = 0; kb < 8; ++kb) bv[kb] = lds_b[cur][rr * 512 + kb * 64 + l];
      const float av[4] = {aj.x, aj.y, aj.z, aj.w};
#pragma unroll
      for (int jp = 0; jp < 4; ++jp)
#pragma unroll
        for (int kb = 0; kb < 8; ++kb)
          acc[jp][kb] = fmaf(av[jp], bv[kb], acc[jp][kb]);
    }
    WAIT_VM(0);
    __syncthreads();
  }

  const int kt = (i * 64 + k0) >> 5;
  const int cw = (k0 & 31) >> 3;
#pragma unroll
  for (int jp = 0; jp < 4; ++jp) {
    const int j = j0 + jj * 4 + jp;
    const int n = j * 64 + l;
    const int blob = (n >> 7) * KT_COUNT + kt;
    const int pos = cw * 128 + (n & 127);
    short8 o;
#pragma unroll
    for (int kb = 0; kb < 8; ++kb) o[kb] = (short)f2bf(acc[jp][kb]);
    *(short8*)(Wp + (size_t)blob * 4096 + pos * 8) = o;
  }
}

// ---------------------------------------------------------------------------
// pack_x: LDS tile transpose. 2048 blocks x 512 threads, 32 KB LDS.
// Block = (M0 0..63, h 0..1, kg 0..15): rows M0*128+h*64 ..+63, k kg*256..+255.
// Read: 4 passes, wave = 2 rows x 512B contiguous; f2bf; store XOR-swizzled
// (chunk col8 ^ (row&31)) -> conflict-free both sides.
// Write: 4 passes x 2 blobs; per wave 1KB contiguous runs.
// Xp blob (M0, kt) = 8KB: chunk (c*128 + mm) holds row mm, k = kt*32+c*8..+7.
// ---------------------------------------------------------------------------
__global__ __launch_bounds__(512) void pack_x_kernel(
    const float* __restrict__ x, unsigned short* __restrict__ Xp) {
  __shared__ short8 smem[2048];  // 32 KB: [64 rows][32 chunks]
  const int pid = blockIdx.x;
  const int M0 = pid >> 5;        // 0..63
  const int h = (pid >> 4) & 1;   // row half of the 128-row panel
  const int kg = pid & 15;        // 256-k group
  const int t = threadIdx.x;

  {
    const int rsub = t >> 5;  // 0..15
    const int col8 = t & 31;  // 16B chunk in the 256-k slice
#pragma unroll
    for (int p = 0; p < 4; ++p) {
      const int rr = p * 16 + rsub;  // 0..63
      const float* src =
          x + (size_t)(M0 * 128 + h * 64 + rr) * K_DIM + kg * 256 + col8 * 8;
      float4 v0 = ((const float4*)src)[0];
      float4 v1 = ((const float4*)src)[1];
      short8 o;
      o[0] = (short)f2bf(v0.x); o[1] = (short)f2bf(v0.y);
      o[2] = (short)f2bf(v0.z); o[3] = (short)f2bf(v0.w);
      o[4] = (short)f2bf(v1.x); o[5] = (short)f2bf(v1.y);
      o[6] = (short)f2bf(v1.z); o[7] = (short)f2bf(v1.w);
      smem[rr * 32 + (col8 ^ (rr & 31))] = o;
    }
  }
  __syncthreads();

  const int ml = t & 63;        // local row
  const int c = (t >> 6) & 3;   // k-chunk within K-step
  const int qh = t >> 8;        // 0..1: blob parity
#pragma unroll
  for (int q = 0; q < 4; ++q) {
    const int qq = q * 2 + qh;       // K-step within the kg group (0..7)
    const int cc = qq * 4 + c;       // chunk col in smem (0..31)
    short8 v = smem[ml * 32 + (cc ^ (ml & 31))];
    unsigned short* dst = Xp + (size_t)(M0 * KT_COUNT + kg * 8 + qq) * 4096 +
                          (size_t)(c * 128 + h * 64 + ml) * 8;
    *(short8*)dst = v;
  }
}

// ---------------------------------------------------------------------------
// GEMM (R1 verbatim, 242-244us measured): C = Xp @ Wp^T + bias.
// 256x256 tile, BK=32, 512 threads (8 waves, 2M x 4N), acc[8][4].
// 4-deep LDS ring; prefetch distance 2; single counted vmcnt(4)/K-step.
// XCD swizzle: bid&7 -> XCD owns 2 N-panels (4MB Wp slice pinned in its L2).
// ---------------------------------------------------------------------------
__global__ __launch_bounds__(512, 2) void gemm_kernel(
    const unsigned short* __restrict__ Xp, const unsigned short* __restrict__ Wp,
    const float* __restrict__ bias, float* __restrict__ out) {
  __shared__ short8 As[4][2][512];  // [ring buf][row half][chunk]  64 KiB
  __shared__ short8 Bs[4][2][512];  // [ring buf][col half][chunk]  64 KiB

  const int bid = blockIdx.x;
  const int xcd = bid & 7;
  const int pos = bid >> 3;            // 0..63
  const int N0 = xcd * 2 + (pos & 1);  // 0..15 (256-col panels)
  const int M0 = pos >> 1;             // 0..31 (256-row panels)

  const int t = threadIdx.x;
  const int wave = t >> 6, lane = t & 63;
  const int l16 = lane & 15, quad = lane >> 4;
  const int wm = wave & 1;   // A half (128 rows)
  const int wn = wave >> 1;  // 0..3 (64-col quarter)

  floatx4 acc[8][4];
#pragma unroll
  for (int mt = 0; mt < 8; ++mt)
#pragma unroll
    for (int nt = 0; nt < 4; ++nt) acc[mt][nt] = (floatx4){0.f, 0.f, 0.f, 0.f};

  const unsigned short* gA0 = Xp + (size_t)(M0 * 2 + 0) * KT_COUNT * 4096 + (size_t)t * 8;
  const unsigned short* gA1 = Xp + (size_t)(M0 * 2 + 1) * KT_COUNT * 4096 + (size_t)t * 8;
  const unsigned short* gB0 = Wp + (size_t)(N0 * 2 + 0) * KT_COUNT * 4096 + (size_t)t * 8;
  const unsigned short* gB1 = Wp + (size_t)(N0 * 2 + 1) * KT_COUNT * 4096 + (size_t)t * 8;

  // ---- prologue: stage K-steps 0 and 1 (8 loads), require step 0 landed.
  gl_lds16(gA0, &As[0][0][t]);
  gl_lds16(gA1, &As[0][1][t]);
  gl_lds16(gB0, &Bs[0][0][t]);
  gl_lds16(gB1, &Bs[0][1][t]);
  gl_lds16(gA0 + 4096, &As[1][0][t]);
  gl_lds16(gA1 + 4096, &As[1][1][t]);
  gl_lds16(gB0 + 4096, &Bs[1][0][t]);
  gl_lds16(gB1 + 4096, &Bs[1][1][t]);
  WAIT_VM(4);  // 4 newest (step 1) may stay in flight; step 0 complete
  BAR();

  const int ra = quad * 128 + l16;                  // A chunk base
  const int rb = quad * 128 + (wn & 1) * 64 + l16;  // B chunk base
  const int bh = wn >> 1;                           // B half

#pragma unroll 2
  for (int kt = 0; kt < KT_COUNT; ++kt) {
    const int tb = kt & 3;
    const int db = (kt + 2) & 3;
    const size_t soff =
        (size_t)((kt + 2 < KT_COUNT) ? kt + 2 : KT_COUNT - 1) * 4096;

    short8 bf[4], af[4];

    // ---------------- phase 0: B frags + A rows 0..63, stage A(t+2)
#pragma unroll
    for (int nt = 0; nt < 4; ++nt) bf[nt] = Bs[tb][bh][rb + nt * 16];
#pragma unroll
    for (int m = 0; m < 4; ++m) af[m] = As[tb][wm][ra + m * 16];
    gl_lds16(gA0 + soff, &As[db][0][t]);
    gl_lds16(gA1 + soff, &As[db][1][t]);
    BAR();
    WAIT_LGKM0();
    __builtin_amdgcn_sched_barrier(0);
    __builtin_amdgcn_s_setprio(1);
#pragma unroll
    for (int m = 0; m < 4; ++m)
#pragma unroll
      for (int nt = 0; nt < 4; ++nt)
        acc[m][nt] = __builtin_amdgcn_mfma_f32_16x16x32_bf16(
            af[m], bf[nt], acc[m][nt], 0, 0, 0);
    __builtin_amdgcn_s_setprio(0);
    __builtin_amdgcn_sched_barrier(0);
    BAR();

    // ---------------- phase 1: A rows 64..127, stage B(t+2), counted vmcnt
#pragma unroll
    for (int m = 0; m < 4; ++m) af[m] = As[tb][wm][ra + (4 + m) * 16];
    gl_lds16(gB0 + soff, &Bs[db][0][t]);
    gl_lds16(gB1 + soff, &Bs[db][1][t]);
    WAIT_VM(4);  // allow the 4 t+2 loads in flight; forces step t+1 landed
    BAR();
    WAIT_LGKM0();
    __builtin_amdgcn_sched_barrier(0);
    __builtin_amdgcn_s_setprio(1);
#pragma unroll
    for (int m = 0; m < 4; ++m)
#pragma unroll
      for (int nt = 0; nt < 4; ++nt)
        acc[4 + m][nt] = __builtin_amdgcn_mfma_f32_16x16x32_bf16(
            af[m], bf[nt], acc[4 + m][nt], 0, 0, 0);
    __builtin_amdgcn_s_setprio(0);
    __builtin_amdgcn_sched_barrier(0);
    BAR();
  }

  // ---- epilogue
  const int col_base = N0 * 256 + wn * 64;
  const int row_base = M0 * 256 + wm * 128;
#pragma unroll
  for (int nt = 0; nt < 4; ++nt) {
    const int col = col_base + nt * 16 + l16;
    const float bv = bias[col];
#pragma unroll
    for (int mt = 0; mt < 8; ++mt) {
      floatx4 v = acc[mt][nt];
#pragma unroll
      for (int r4 = 0; r4 < 4; ++r4) {
        const int row = row_base + mt * 16 + quad * 4 + r4;
        out[(size_t)row * N_DIM + col] = v[r4] + bv;
      }
    }
  }
}

extern "C" void kernel_launch(void* const* d_in, const int* in_sizes, int n_in,
                              void* d_out, int out_size, void* d_ws, size_t ws_size,
                              hipStream_t stream) {
  const float* x = (const float*)d_in[0];     // 8192*4096
  const float* a = (const float*)d_in[1];     // 64*64*64 (r,i,j)
  const float* b = (const float*)d_in[2];     // 64*64*64 (r,k,l)
  const float* bias = (const float*)d_in[3];  // 4096
  float* out = (float*)d_out;

  unsigned short* Xp = (unsigned short*)d_ws;        // 67MB
  unsigned short* Wp = Xp + (size_t)M_DIM * K_DIM;   // 33.5MB

  build_w_kernel<<<2048, 256, 0, stream>>>(a, b, Wp);
  pack_x_kernel<<<2048, 512, 0, stream>>>(x, Xp);
  gemm_kernel<<<512, 512, 0, stream>>>(Xp, Wp, bias, out);
}